// Round 2
// baseline (1082.797 us; speedup 1.0000x reference)
//
#include <hip/hip_runtime.h>
#include <hip/hip_bf16.h>

#define TT 2048
#define BB 16
#define DD 1024
#define BD (BB*DD)          // 16384 cols per time row
#define MR (TT*BB)          // 32768 GEMM rows
#define EPSV 1e-6f
#define CH 256              // phase-B chunk length
#define NCH (TT/CH)         // 8
#define RING 12             // phase-A LDS ring depth (rows)

typedef __bf16 bf16x8_t __attribute__((ext_vector_type(8)));
typedef float  f32x4_t  __attribute__((ext_vector_type(4)));
typedef __attribute__((address_space(1))) void gvoid_t;
typedef __attribute__((address_space(3))) void lvoid_t;

static __device__ __forceinline__ unsigned short f2bf(float f) {
    __hip_bfloat16 h = __float2bfloat16(f);
    return __builtin_bit_cast(unsigned short, h);
}

// ---------------------------------------------------------------------------
// K0: convert x and W to bf16 (stored in the h-region of d_out, dead space
// until phase A/B overwrite it after the GEMM has consumed it).
// ---------------------------------------------------------------------------
__global__ void k_convert(const float* __restrict__ x, const float* __restrict__ W,
                          unsigned short* __restrict__ xb, unsigned short* __restrict__ wb) {
    const long NX4 = (long)MR * DD / 4;
    const long NW4 = (long)DD * DD / 4;
    const long stride = (long)gridDim.x * blockDim.x;
    for (long j = (long)blockIdx.x * blockDim.x + threadIdx.x; j < NX4 + NW4; j += stride) {
        const float4* src; unsigned short* dst; long o;
        if (j < NX4) { src = (const float4*)x; dst = xb; o = j; }
        else         { src = (const float4*)W; dst = wb; o = j - NX4; }
        float4 v = src[o];
        ushort4 u;
        u.x = f2bf(v.x); u.y = f2bf(v.y); u.z = f2bf(v.z); u.w = f2bf(v.w);
        *(ushort4*)(dst + o * 4) = u;
    }
}

// ---------------------------------------------------------------------------
// K1: Wx = x @ W^T + b  (bf16 MFMA, f32 accumulate/output). Unchanged.
// ---------------------------------------------------------------------------
__global__ __launch_bounds__(256, 2)
void k_gemm(const unsigned short* __restrict__ A, const unsigned short* __restrict__ Bw,
            const float* __restrict__ bias, float* __restrict__ C) {
    __shared__ char lds[16384];
    char* ldsA = lds;
    char* ldsB = lds + 8192;
    const int tid  = threadIdx.x;
    const int lane = tid & 63;
    const int wid  = tid >> 6;
    const int wm = wid >> 1, wn = wid & 1;
    const size_t arow0 = (size_t)blockIdx.y * 128;
    const int    brow0 = blockIdx.x * 128;

    f32x4_t acc[4][4] = {};

    const int off0 = tid * 16,        row0_ = off0 >> 6, colb0 = off0 & 63;
    const int off1 = 4096 + tid * 16, row1_ = off1 >> 6, colb1 = off1 & 63;

    for (int kk = 0; kk < DD / 32; ++kk) {
        const int kbase = kk * 32;
        __builtin_amdgcn_global_load_lds(
            (gvoid_t*)(A + (arow0 + row0_) * DD + kbase + (colb0 >> 1)),
            (lvoid_t*)(ldsA + off0), 16, 0, 0);
        __builtin_amdgcn_global_load_lds(
            (gvoid_t*)(A + (arow0 + row1_) * DD + kbase + (colb1 >> 1)),
            (lvoid_t*)(ldsA + off1), 16, 0, 0);
        __builtin_amdgcn_global_load_lds(
            (gvoid_t*)(Bw + (size_t)(brow0 + row0_) * DD + kbase + (colb0 >> 1)),
            (lvoid_t*)(ldsB + off0), 16, 0, 0);
        __builtin_amdgcn_global_load_lds(
            (gvoid_t*)(Bw + (size_t)(brow0 + row1_) * DD + kbase + (colb1 >> 1)),
            (lvoid_t*)(ldsB + off1), 16, 0, 0);
        __syncthreads();

        const int ml = lane & 15;
        const int kh = (lane >> 4) * 16;
        bf16x8_t av[4], bv[4];
        #pragma unroll
        for (int i = 0; i < 4; ++i) {
            av[i] = *(const bf16x8_t*)(ldsA + (wm * 64 + i * 16 + ml) * 64 + kh);
            bv[i] = *(const bf16x8_t*)(ldsB + (wn * 64 + i * 16 + ml) * 64 + kh);
        }
        #pragma unroll
        for (int i = 0; i < 4; ++i)
            #pragma unroll
            for (int j = 0; j < 4; ++j)
                acc[i][j] = __builtin_amdgcn_mfma_f32_16x16x32_bf16(av[i], bv[j], acc[i][j], 0, 0, 0);
        __syncthreads();
    }

    const int rq = (lane >> 4) * 4;
    const int cl = lane & 15;
    #pragma unroll
    for (int i = 0; i < 4; ++i) {
        #pragma unroll
        for (int j = 0; j < 4; ++j) {
            const int n = brow0 + wn * 64 + j * 16 + cl;
            const float bb = bias[n];
            #pragma unroll
            for (int q = 0; q < 4; ++q) {
                const size_t m = arow0 + wm * 64 + i * 16 + rq + q;
                C[m * DD + n] = acc[i][j][q] + bb;
            }
        }
    }
}

// ---------------------------------------------------------------------------
// K2: phase A — sequential scan, one wave per batch row, h in registers.
// v2: (a) 12-row LDS ring staged via global_load_lds with counted vmcnt
//     (loads fully off the dependence chain, ~1300cy lead > HBM latency);
//     (b) DPP-based wave64 reduction (VALU, ~50cy) replaces 6x shfl_xor
//     (DS pipe, ~300cy); (c) next-row LDS fragment prefetched during
//     current step's compute.
// ---------------------------------------------------------------------------
__global__ __launch_bounds__(64, 1)
void k_phaseA(const float* __restrict__ Wx, const float* __restrict__ h0,
              const float* __restrict__ la, float* __restrict__ hout,
              float* __restrict__ rtab) {
    __shared__ float ring[RING * DD];   // 48 KB
    __shared__ float rbuf[TT];          // 8 KB
    const int b = blockIdx.x;
    const int lane = threadIdx.x;
    const float alpha = expf(la[0]);
    const int dof = lane * 4;           // this lane's offset within each 256-float group
    const float* wbase = Wx + b * DD;

    float h[16];
    #pragma unroll
    for (int k = 0; k < 4; ++k) {
        float4 v = *(const float4*)(h0 + b * DD + k * 256 + dof);
        h[k*4+0] = v.x; h[k*4+1] = v.y; h[k*4+2] = v.z; h[k*4+3] = v.w;
    }

    // prologue: issue DMA for rows t=1..RING (Wx row index t-1 -> slot t-1)
    for (int s = 0; s < RING; ++s) {
        const float* wp = wbase + (size_t)s * BD;
        #pragma unroll
        for (int k = 0; k < 4; ++k)
            __builtin_amdgcn_global_load_lds((gvoid_t*)(wp + k * 256 + dof),
                                             (lvoid_t*)(ring + s * DD + k * 256), 16, 0, 0);
    }
    // wait until row t=1 landed (oldest 4 of 48 outstanding), preload it
    asm volatile("s_waitcnt vmcnt(%0)" :: "i"(4 * (RING - 1)) : "memory");
    float4 cur[4];
    #pragma unroll
    for (int k = 0; k < 4; ++k) cur[k] = *(const float4*)(ring + k * 256 + dof);

    int slot = 0;   // slot of row t
    for (int t = 1; t <= TT; ++t) {
        const int nslot = (slot + 1 == RING) ? 0 : slot + 1;

        if (((t - 1) & (CH - 1)) == 0) {            // snapshot h_{t-1}
            float* hp = hout + (size_t)(t - 1) * BD + b * DD;
            #pragma unroll
            for (int k = 0; k < 4; ++k) {
                float4 v; v.x = h[k*4+0]; v.y = h[k*4+1]; v.z = h[k*4+2]; v.w = h[k*4+3];
                *(float4*)(hp + k * 256 + dof) = v;
            }
        }

        // rows t and t+1 are both complete once <= 4*(RING-2) loads outstanding
        asm volatile("s_waitcnt vmcnt(%0)" :: "i"(4 * (RING - 2)) : "memory");
        float4 nxt[4];
        #pragma unroll
        for (int k = 0; k < 4; ++k) nxt[k] = *(const float4*)(ring + nslot * DD + k * 256 + dof);

        // ---- dependence chain ----
        float hr[16];
        float s0 = 0.f, s1 = 0.f, s2 = 0.f, s3 = 0.f;
        #pragma unroll
        for (int k = 0; k < 4; ++k) {
            hr[k*4+0] = fmaf(alpha, cur[k].x, h[k*4+0]);
            hr[k*4+1] = fmaf(alpha, cur[k].y, h[k*4+1]);
            hr[k*4+2] = fmaf(alpha, cur[k].z, h[k*4+2]);
            hr[k*4+3] = fmaf(alpha, cur[k].w, h[k*4+3]);
            s0 = fmaf(hr[k*4+0], hr[k*4+0], s0);
            s1 = fmaf(hr[k*4+1], hr[k*4+1], s1);
            s2 = fmaf(hr[k*4+2], hr[k*4+2], s2);
            s3 = fmaf(hr[k*4+3], hr[k*4+3], s3);
        }
        float ss = (s0 + s1) + (s2 + s3);
        // canonical GCN wave64 DPP sum -> total in lane 63 (s_nop covers DPP hazard)
        asm volatile(
            "s_nop 1\n\t"
            "v_add_f32 %0, %0, %0 row_shr:1 bound_ctrl:0\n\t"
            "s_nop 1\n\t"
            "v_add_f32 %0, %0, %0 row_shr:2 bound_ctrl:0\n\t"
            "s_nop 1\n\t"
            "v_add_f32 %0, %0, %0 row_shr:4 bank_mask:0xe\n\t"
            "s_nop 1\n\t"
            "v_add_f32 %0, %0, %0 row_shr:8 bank_mask:0xc\n\t"
            "s_nop 1\n\t"
            "v_add_f32 %0, %0, %0 row_bcast:15 row_mask:0xa\n\t"
            "s_nop 1\n\t"
            "v_add_f32 %0, %0, %0 row_bcast:31 row_mask:0xc\n\t"
            "s_nop 1"
            : "+v"(ss));
        const float total = __builtin_bit_cast(float,
                                __builtin_amdgcn_readlane(__builtin_bit_cast(int, ss), 63));
        const float r = rsqrtf(total * (1.0f / DD) + EPSV);
        if (lane == 0) rbuf[t - 1] = r;
        #pragma unroll
        for (int e = 0; e < 16; ++e) h[e] = r * hr[e];
        // ---- end chain ----

        // refill slot with row t+RING (wrapped index past the end: dummy, never read)
        asm volatile("s_waitcnt lgkmcnt(0)" ::: "memory");
        const int rr = (t + RING - 1) & (TT - 1);
        const float* wp = wbase + (size_t)rr * BD;
        #pragma unroll
        for (int k = 0; k < 4; ++k)
            __builtin_amdgcn_global_load_lds((gvoid_t*)(wp + k * 256 + dof),
                                             (lvoid_t*)(ring + slot * DD + k * 256), 16, 0, 0);

        #pragma unroll
        for (int k = 0; k < 4; ++k) cur[k] = nxt[k];
        slot = nslot;
    }

    // flush r-table: 2048 floats = 8 float4 per lane
    float* rrow = rtab + b * TT;
    #pragma unroll
    for (int i = 0; i < TT / 4 / 64; ++i) {
        const int j = (i * 64 + lane) * 4;
        float4 v; v.x = rbuf[j]; v.y = rbuf[j+1]; v.z = rbuf[j+2]; v.w = rbuf[j+3];
        *(float4*)(rrow + j) = v;
    }
}

// ---------------------------------------------------------------------------
// K3: phase B — parallel replay. Unchanged.
// ---------------------------------------------------------------------------
__global__ __launch_bounds__(256)
void k_phaseB(float* __restrict__ WxOut, float* __restrict__ hout,
              const float* __restrict__ rtab, const float* __restrict__ la) {
    const int col = blockIdx.x * 256 + threadIdx.x;
    const int c = blockIdx.y;
    const int b = col >> 10;
    const float alpha = expf(la[0]);
    const float* rr = rtab + b * TT;
    float h = hout[(size_t)(c * CH) * BD + col];
    const int t0 = c * CH + 1;
    float w = WxOut[(size_t)(t0 - 1) * BD + col];
    for (int s = 0; s < CH; ++s) {
        const int t = t0 + s;
        float wnext = 0.f;
        if (s + 1 < CH) wnext = WxOut[(size_t)t * BD + col];
        const float r = rr[t - 1];
        const float hraw = fmaf(alpha, w, h);
        const float hn = r * hraw;
        const float sg = 1.0f / (1.0f + __expf(-hn));
        WxOut[(size_t)(t - 1) * BD + col] = hn * hn * sg;
        if ((t & (CH - 1)) != 0 || t == TT)
            hout[(size_t)t * BD + col] = hn;
        h = hn;
        w = wnext;
    }
}

// ---------------------------------------------------------------------------
extern "C" void kernel_launch(void* const* d_in, const int* in_sizes, int n_in,
                              void* d_out, int out_size, void* d_ws, size_t ws_size,
                              hipStream_t stream) {
    (void)in_sizes; (void)n_in; (void)out_size; (void)ws_size;
    const float* x    = (const float*)d_in[0];
    const float* h0   = (const float*)d_in[1];
    const float* W    = (const float*)d_in[2];
    const float* bias = (const float*)d_in[3];
    const float* la   = (const float*)d_in[4];

    float* outr = (float*)d_out;                       // [T][B*D] : Wx, then out
    float* hreg = outr + (size_t)TT * BD;              // [T+1][B*D] : h output
    unsigned short* xb = (unsigned short*)hreg;        // bf16 x (dead space pre-phase-A)
    unsigned short* wb = xb + (size_t)MR * DD;         // bf16 W
    float* rtab = (float*)d_ws;                        // [B][T] = 128KB

    k_convert<<<2048, 256, 0, stream>>>(x, W, xb, wb);
    k_gemm<<<dim3(DD / 128, MR / 128), 256, 0, stream>>>(xb, wb, bias, outr);
    k_phaseA<<<BB, 64, 0, stream>>>(outr, h0, la, hreg, rtab);
    k_phaseB<<<dim3(BD / 256, NCH), 256, 0, stream>>>(outr, hreg, rtab, la);
}

// Round 3
// 507.934 us; speedup vs baseline: 2.1318x; 2.1318x over previous
//
#include <hip/hip_runtime.h>
#include <hip/hip_bf16.h>

#define TT 2048
#define BB 16
#define DD 1024
#define BD (BB*DD)          // 16384 cols per time row
#define MR (TT*BB)          // 32768 GEMM rows
#define EPSV 1e-6f
#define CH 256              // phase-B chunk length
#define NCH (TT/CH)         // 8
#define RING 8              // phase-A register ring depth (rows)

typedef __bf16 bf16x8_t __attribute__((ext_vector_type(8)));
typedef float  f32x4_t  __attribute__((ext_vector_type(4)));
typedef __attribute__((address_space(1))) void gvoid_t;
typedef __attribute__((address_space(3))) void lvoid_t;

static __device__ __forceinline__ unsigned short f2bf(float f) {
    __hip_bfloat16 h = __float2bfloat16(f);
    return __builtin_bit_cast(unsigned short, h);
}

// ---------------------------------------------------------------------------
// K0: convert x and W to bf16 (stored in the h-region of d_out, dead space
// until phase A/B overwrite it after the GEMM has consumed it).
// ---------------------------------------------------------------------------
__global__ void k_convert(const float* __restrict__ x, const float* __restrict__ W,
                          unsigned short* __restrict__ xb, unsigned short* __restrict__ wb) {
    const long NX4 = (long)MR * DD / 4;
    const long NW4 = (long)DD * DD / 4;
    const long stride = (long)gridDim.x * blockDim.x;
    for (long j = (long)blockIdx.x * blockDim.x + threadIdx.x; j < NX4 + NW4; j += stride) {
        const float4* src; unsigned short* dst; long o;
        if (j < NX4) { src = (const float4*)x; dst = xb; o = j; }
        else         { src = (const float4*)W; dst = wb; o = j - NX4; }
        float4 v = src[o];
        ushort4 u;
        u.x = f2bf(v.x); u.y = f2bf(v.y); u.z = f2bf(v.z); u.w = f2bf(v.w);
        *(ushort4*)(dst + o * 4) = u;
    }
}

// ---------------------------------------------------------------------------
// K1: Wx = x @ W^T + b  (bf16 MFMA, f32 accumulate/output). Unchanged.
// ---------------------------------------------------------------------------
__global__ __launch_bounds__(256, 2)
void k_gemm(const unsigned short* __restrict__ A, const unsigned short* __restrict__ Bw,
            const float* __restrict__ bias, float* __restrict__ C) {
    __shared__ char lds[16384];
    char* ldsA = lds;
    char* ldsB = lds + 8192;
    const int tid  = threadIdx.x;
    const int lane = tid & 63;
    const int wid  = tid >> 6;
    const int wm = wid >> 1, wn = wid & 1;
    const size_t arow0 = (size_t)blockIdx.y * 128;
    const int    brow0 = blockIdx.x * 128;

    f32x4_t acc[4][4] = {};

    const int off0 = tid * 16,        row0_ = off0 >> 6, colb0 = off0 & 63;
    const int off1 = 4096 + tid * 16, row1_ = off1 >> 6, colb1 = off1 & 63;

    for (int kk = 0; kk < DD / 32; ++kk) {
        const int kbase = kk * 32;
        __builtin_amdgcn_global_load_lds(
            (gvoid_t*)(A + (arow0 + row0_) * DD + kbase + (colb0 >> 1)),
            (lvoid_t*)(ldsA + off0), 16, 0, 0);
        __builtin_amdgcn_global_load_lds(
            (gvoid_t*)(A + (arow0 + row1_) * DD + kbase + (colb1 >> 1)),
            (lvoid_t*)(ldsA + off1), 16, 0, 0);
        __builtin_amdgcn_global_load_lds(
            (gvoid_t*)(Bw + (size_t)(brow0 + row0_) * DD + kbase + (colb0 >> 1)),
            (lvoid_t*)(ldsB + off0), 16, 0, 0);
        __builtin_amdgcn_global_load_lds(
            (gvoid_t*)(Bw + (size_t)(brow0 + row1_) * DD + kbase + (colb1 >> 1)),
            (lvoid_t*)(ldsB + off1), 16, 0, 0);
        __syncthreads();

        const int ml = lane & 15;
        const int kh = (lane >> 4) * 16;
        bf16x8_t av[4], bv[4];
        #pragma unroll
        for (int i = 0; i < 4; ++i) {
            av[i] = *(const bf16x8_t*)(ldsA + (wm * 64 + i * 16 + ml) * 64 + kh);
            bv[i] = *(const bf16x8_t*)(ldsB + (wn * 64 + i * 16 + ml) * 64 + kh);
        }
        #pragma unroll
        for (int i = 0; i < 4; ++i)
            #pragma unroll
            for (int j = 0; j < 4; ++j)
                acc[i][j] = __builtin_amdgcn_mfma_f32_16x16x32_bf16(av[i], bv[j], acc[i][j], 0, 0, 0);
        __syncthreads();
    }

    const int rq = (lane >> 4) * 4;
    const int cl = lane & 15;
    #pragma unroll
    for (int i = 0; i < 4; ++i) {
        #pragma unroll
        for (int j = 0; j < 4; ++j) {
            const int n = brow0 + wn * 64 + j * 16 + cl;
            const float bb = bias[n];
            #pragma unroll
            for (int q = 0; q < 4; ++q) {
                const size_t m = arow0 + wm * 64 + i * 16 + rq + q;
                C[m * DD + n] = acc[i][j][q] + bb;
            }
        }
    }
}

// ---------------------------------------------------------------------------
// K2: phase A v3 — sequential scan, one wave per batch row, h in registers.
// Register prefetch ring via inline-asm global_load_dwordx4 (opaque to the
// compiler's waitcnt insertion -> no forced vmcnt(0) drains; v2's LDS-ring
// failure mode). Counted s_waitcnt vmcnt(4*(RING-1)) + sched_barrier(0)
// provides the only ordering. DPP wave64 reduction (VALU ~50cy) instead of
// 6 dependent ds_bpermute (~660cy) -- v1's dominant serial cost.
// ---------------------------------------------------------------------------
__global__ __launch_bounds__(64, 1)
void k_phaseA(const float* __restrict__ Wx, const float* __restrict__ h0,
              const float* __restrict__ la, float* __restrict__ hout,
              float* __restrict__ rtab) {
    __shared__ float rbuf[TT];          // 8 KB r-table staging
    const int b = blockIdx.x;
    const int lane = threadIdx.x;
    const float alpha = expf(la[0]);
    const int dof = lane * 4;           // this lane's offset within each 256-float group
    const float* wbase = Wx + b * DD + dof;

    float h[16];
    #pragma unroll
    for (int k = 0; k < 4; ++k) {
        float4 v = *(const float4*)(h0 + b * DD + k * 256 + dof);
        h[k*4+0] = v.x; h[k*4+1] = v.y; h[k*4+2] = v.z; h[k*4+3] = v.w;
    }
    // Force the h0 loads' compiler-inserted waitcnt to land HERE, before the
    // ring issues (otherwise it defers a vmcnt(0) into the first loop body
    // and drains the ring once).
    asm volatile("" :: "v"(h[0]), "v"(h[1]), "v"(h[2]), "v"(h[3]),
                       "v"(h[4]), "v"(h[5]), "v"(h[6]), "v"(h[7]),
                       "v"(h[8]), "v"(h[9]), "v"(h[10]), "v"(h[11]),
                       "v"(h[12]), "v"(h[13]), "v"(h[14]), "v"(h[15]));

    // prologue: issue rows 0..RING-1 (Wx row t-1 feeds step t)
    f32x4_t buf[RING][4];
    #pragma unroll
    for (int s = 0; s < RING; ++s) {
        const float* wp = wbase + (size_t)s * BD;
        #pragma unroll
        for (int k = 0; k < 4; ++k)
            asm volatile("global_load_dwordx4 %0, %1, off"
                         : "=v"(buf[s][k]) : "v"(wp + k * 256));
    }

    for (int tt = 0; tt < TT; tt += RING) {
        #pragma unroll
        for (int s = 0; s < RING; ++s) {
            const int t = tt + s + 1;

            if (((t - 1) & (CH - 1)) == 0) {            // snapshot h_{t-1}
                float* hp = hout + (size_t)(t - 1) * BD + b * DD;
                #pragma unroll
                for (int k = 0; k < 4; ++k) {
                    float4 v; v.x = h[k*4+0]; v.y = h[k*4+1]; v.z = h[k*4+2]; v.w = h[k*4+3];
                    *(float4*)(hp + k * 256 + dof) = v;
                }
            }

            // row t's 4 loads are the oldest outstanding; in-order vmcnt
            // retirement means waiting to 4*(RING-1) completes them (the
            // occasional snapshot stores are newer -> never under-waits).
            asm volatile("s_waitcnt vmcnt(%0)" :: "i"(4 * (RING - 1)) : "memory");
            __builtin_amdgcn_sched_barrier(0);

            // ---- dependence chain ----
            float hr[16];
            float s0 = 0.f, s1 = 0.f, s2 = 0.f, s3 = 0.f;
            #pragma unroll
            for (int k = 0; k < 4; ++k) {
                const f32x4_t w = buf[s][k];
                hr[k*4+0] = fmaf(alpha, w[0], h[k*4+0]);
                hr[k*4+1] = fmaf(alpha, w[1], h[k*4+1]);
                hr[k*4+2] = fmaf(alpha, w[2], h[k*4+2]);
                hr[k*4+3] = fmaf(alpha, w[3], h[k*4+3]);
                s0 = fmaf(hr[k*4+0], hr[k*4+0], s0);
                s1 = fmaf(hr[k*4+1], hr[k*4+1], s1);
                s2 = fmaf(hr[k*4+2], hr[k*4+2], s2);
                s3 = fmaf(hr[k*4+3], hr[k*4+3], s3);
            }
            float ss = (s0 + s1) + (s2 + s3);
            // wave64 DPP sum -> total in lane 63 (numerically verified in v2)
            asm volatile(
                "s_nop 1\n\t"
                "v_add_f32 %0, %0, %0 row_shr:1 bound_ctrl:0\n\t"
                "s_nop 1\n\t"
                "v_add_f32 %0, %0, %0 row_shr:2 bound_ctrl:0\n\t"
                "s_nop 1\n\t"
                "v_add_f32 %0, %0, %0 row_shr:4 bank_mask:0xe\n\t"
                "s_nop 1\n\t"
                "v_add_f32 %0, %0, %0 row_shr:8 bank_mask:0xc\n\t"
                "s_nop 1\n\t"
                "v_add_f32 %0, %0, %0 row_bcast:15 row_mask:0xa\n\t"
                "s_nop 1\n\t"
                "v_add_f32 %0, %0, %0 row_bcast:31 row_mask:0xc\n\t"
                "s_nop 1"
                : "+v"(ss));
            const float total = __builtin_bit_cast(float,
                                    __builtin_amdgcn_readlane(__builtin_bit_cast(int, ss), 63));
            const float r = __builtin_amdgcn_rsqf(total * (1.0f / DD) + EPSV);
            if (lane == 0) rbuf[t - 1] = r;
            #pragma unroll
            for (int e = 0; e < 16; ++e) h[e] = r * hr[e];
            // ---- end chain ----

            // refill slot s with row t-1+RING (wrapped past the end: dummy)
            const float* wp = wbase + (size_t)((t - 1 + RING) & (TT - 1)) * BD;
            #pragma unroll
            for (int k = 0; k < 4; ++k)
                asm volatile("global_load_dwordx4 %0, %1, off"
                             : "=v"(buf[s][k]) : "v"(wp + k * 256));
        }
    }

    // drain remaining ring loads before touching their regs / ending the wave
    asm volatile("s_waitcnt vmcnt(0)" ::: "memory");

    // flush r-table: 2048 floats = 8 float4 per lane
    __syncthreads();
    float* rrow = rtab + b * TT;
    #pragma unroll
    for (int i = 0; i < TT / 4 / 64; ++i) {
        const int j = (i * 64 + lane) * 4;
        float4 v; v.x = rbuf[j]; v.y = rbuf[j+1]; v.z = rbuf[j+2]; v.w = rbuf[j+3];
        *(float4*)(rrow + j) = v;
    }
}

// ---------------------------------------------------------------------------
// K3: phase B — parallel replay. Unchanged.
// ---------------------------------------------------------------------------
__global__ __launch_bounds__(256)
void k_phaseB(float* __restrict__ WxOut, float* __restrict__ hout,
              const float* __restrict__ rtab, const float* __restrict__ la) {
    const int col = blockIdx.x * 256 + threadIdx.x;
    const int c = blockIdx.y;
    const int b = col >> 10;
    const float alpha = expf(la[0]);
    const float* rr = rtab + b * TT;
    float h = hout[(size_t)(c * CH) * BD + col];
    const int t0 = c * CH + 1;
    float w = WxOut[(size_t)(t0 - 1) * BD + col];
    for (int s = 0; s < CH; ++s) {
        const int t = t0 + s;
        float wnext = 0.f;
        if (s + 1 < CH) wnext = WxOut[(size_t)t * BD + col];
        const float r = rr[t - 1];
        const float hraw = fmaf(alpha, w, h);
        const float hn = r * hraw;
        const float sg = 1.0f / (1.0f + __expf(-hn));
        WxOut[(size_t)(t - 1) * BD + col] = hn * hn * sg;
        if ((t & (CH - 1)) != 0 || t == TT)
            hout[(size_t)t * BD + col] = hn;
        h = hn;
        w = wnext;
    }
}

// ---------------------------------------------------------------------------
extern "C" void kernel_launch(void* const* d_in, const int* in_sizes, int n_in,
                              void* d_out, int out_size, void* d_ws, size_t ws_size,
                              hipStream_t stream) {
    (void)in_sizes; (void)n_in; (void)out_size; (void)ws_size;
    const float* x    = (const float*)d_in[0];
    const float* h0   = (const float*)d_in[1];
    const float* W    = (const float*)d_in[2];
    const float* bias = (const float*)d_in[3];
    const float* la   = (const float*)d_in[4];

    float* outr = (float*)d_out;                       // [T][B*D] : Wx, then out
    float* hreg = outr + (size_t)TT * BD;              // [T+1][B*D] : h output
    unsigned short* xb = (unsigned short*)hreg;        // bf16 x (dead space pre-phase-A)
    unsigned short* wb = xb + (size_t)MR * DD;         // bf16 W
    float* rtab = (float*)d_ws;                        // [B][T] = 128KB

    k_convert<<<2048, 256, 0, stream>>>(x, W, xb, wb);
    k_gemm<<<dim3(DD / 128, MR / 128), 256, 0, stream>>>(xb, wb, bias, outr);
    k_phaseA<<<BB, 64, 0, stream>>>(outr, h0, la, hreg, rtab);
    k_phaseB<<<dim3(BD / 256, NCH), 256, 0, stream>>>(outr, hreg, rtab, la);
}